// Round 7
// baseline (329.529 us; speedup 1.0000x reference)
//
#include <hip/hip_runtime.h>

#define CAP_I   65536        // incident edges (expected ~64)
#define CAP_S1  (1 << 18)    // S1 nodes (expected ~2K)
#define CAP_L2  (1 << 20)    // edges into T (expected ~2K)
#define CAP_L1  (1 << 22)    // edges into S1 (expected ~64K)
#define LBUF    2560         // per-block LDS append buffer (entries)
#define FLUSH_THRESH 512     // LBUF - FLUSH_THRESH >= 512 threads * 4 edges
#define NWMAX   15680        // bitmap words: supports N <= 501,760

typedef unsigned int uint;
typedef float vfloat4 __attribute__((ext_vector_type(4)));   // for nontemporal stores

// ---- pass A: stream src+dst, collect incident edges (no output writes) ----
__global__ void k_passA(const int4* __restrict__ src4, const int4* __restrict__ dst4, int nvec,
                        const int* __restrict__ nodep,
                        int* __restrict__ cnts, int* __restrict__ le, int* __restrict__ lt) {
    int node = *nodep;
    int stride = gridDim.x * blockDim.x;
    for (int v = blockIdx.x * blockDim.x + threadIdx.x; v < nvec; v += stride) {
        int4 s4 = src4[v];
        int4 d4 = dst4[v];
        int ss[4] = {s4.x, s4.y, s4.z, s4.w};
        int dd[4] = {d4.x, d4.y, d4.z, d4.w};
#pragma unroll
        for (int k = 0; k < 4; k++) {
            if (ss[k] == node || dd[k] == node) {
                int t = (ss[k] == node) ? dd[k] : ss[k];
                int pos = atomicAdd(&cnts[0], 1);
                if (pos < CAP_I) { le[pos] = v * 4 + k; lt[pos] = t; }
            }
        }
    }
}

// ---- mark T, seed S1/S0 with T; first-touch zero deg/acc1/acc2 ----
__global__ void k_markT(const int* __restrict__ cnts, const int* __restrict__ lt,
                        uint* __restrict__ bmT, uint* __restrict__ bmS1,
                        uint* __restrict__ bmS0,
                        int* __restrict__ cnts_w, int* __restrict__ s1list,
                        int* __restrict__ deg, float4* __restrict__ acc1,
                        float4* __restrict__ acc2) {
    int n = cnts[0]; if (n > CAP_I) n = CAP_I;
    const float4 z4 = make_float4(0.f, 0.f, 0.f, 0.f);
    for (int i = threadIdx.x; i < n; i += blockDim.x) {
        int t = lt[i];
        uint bit = 1u << (t & 31);
        atomicOr(&bmT[t >> 5], bit);
        uint old = atomicOr(&bmS1[t >> 5], bit);
        if (!(old & bit)) {
            atomicOr(&bmS0[t >> 5], bit);
            deg[t] = 0; acc1[t] = z4; acc2[t] = z4;
            int p = atomicAdd(&cnts_w[2], 1);
            if (p < CAP_S1) s1list[p] = t;
        }
    }
}

// ---- pass B: dst in T -> L2 edge list, srcs -> S1 (LDS bitmap + LDS appends) ----
__global__ __launch_bounds__(512) void k_passB(
        const int* __restrict__ src, const int4* __restrict__ dst4, int nvec, int NW,
        const uint* __restrict__ bmT, uint* __restrict__ bmS1, uint* __restrict__ bmS0,
        int* __restrict__ cnts, int* __restrict__ l2s, int* __restrict__ l2t,
        int* __restrict__ s1list,
        int* __restrict__ deg, float4* __restrict__ acc1, float4* __restrict__ acc2) {
    __shared__ uint lT[NWMAX];
    __shared__ int bes[LBUF], bet[LBUF], bs1[LBUF];
    __shared__ int lcE, lcS, gbE, gbS;
    for (int i = threadIdx.x; i < NW; i += blockDim.x) lT[i] = bmT[i];
    if (threadIdx.x == 0) { lcE = 0; lcS = 0; }
    __syncthreads();
    const float4 z4 = make_float4(0.f, 0.f, 0.f, 0.f);
    int tid0 = blockIdx.x * blockDim.x + threadIdx.x;
    int stride = gridDim.x * blockDim.x;
    int itersU = (nvec + stride - 1) / stride;
    for (int it = 0; it < itersU; ++it) {
        int v = tid0 + it * stride;
        if (v < nvec) {
            int4 d4 = dst4[v];
            int dd[4] = {d4.x, d4.y, d4.z, d4.w};
#pragma unroll
            for (int k = 0; k < 4; k++) {
                int d = dd[k];
                if ((lT[d >> 5] >> (d & 31)) & 1u) {
                    int s = src[v * 4 + k];
                    int p = atomicAdd(&lcE, 1);
                    if (p < LBUF) { bes[p] = s; bet[p] = d; }
                    uint bit = 1u << (s & 31);
                    uint old = atomicOr(&bmS1[s >> 5], bit);
                    if (!(old & bit)) {
                        atomicOr(&bmS0[s >> 5], bit);
                        deg[s] = 0; acc1[s] = z4; acc2[s] = z4;
                        int q = atomicAdd(&lcS, 1);
                        if (q < LBUF) bs1[q] = s;
                    }
                }
            }
        }
        __syncthreads();
        if (lcE > FLUSH_THRESH || lcS > FLUSH_THRESH) {
            int nE = min(lcE, LBUF), nS = min(lcS, LBUF);
            if (threadIdx.x == 0) {
                gbE = atomicAdd(&cnts[1], nE);
                gbS = atomicAdd(&cnts[2], nS);
            }
            __syncthreads();
            for (int i = threadIdx.x; i < nE; i += blockDim.x) {
                int pos = gbE + i;
                if (pos < CAP_L2) { l2s[pos] = bes[i]; l2t[pos] = bet[i]; }
            }
            for (int i = threadIdx.x; i < nS; i += blockDim.x) {
                int pos = gbS + i;
                if (pos < CAP_S1) s1list[pos] = bs1[i];
            }
            __syncthreads();
            if (threadIdx.x == 0) { lcE = 0; lcS = 0; }
        }
        __syncthreads();
    }
    int nE = min(lcE, LBUF), nS = min(lcS, LBUF);
    if (nE > 0 || nS > 0) {
        if (threadIdx.x == 0) {
            gbE = atomicAdd(&cnts[1], nE);
            gbS = atomicAdd(&cnts[2], nS);
        }
        __syncthreads();
        for (int i = threadIdx.x; i < nE; i += blockDim.x) {
            int pos = gbE + i;
            if (pos < CAP_L2) { l2s[pos] = bes[i]; l2t[pos] = bet[i]; }
        }
        for (int i = threadIdx.x; i < nS; i += blockDim.x) {
            int pos = gbS + i;
            if (pos < CAP_S1) s1list[pos] = bs1[i];
        }
    }
}

// ---- pass C: dst in S1 -> L1 edge list, srcs -> S0 (first-touch zero deg) ----
__global__ __launch_bounds__(512) void k_passC(
        const int* __restrict__ src, const int4* __restrict__ dst4, int nvec, int NW,
        const uint* __restrict__ bmS1, uint* __restrict__ bmS0,
        int* __restrict__ cnts, int* __restrict__ l1s, int* __restrict__ l1t,
        int* __restrict__ deg) {
    __shared__ uint lS1[NWMAX];
    __shared__ int lbs[LBUF], lbt[LBUF];
    __shared__ int lcnt, gbase;
    for (int i = threadIdx.x; i < NW; i += blockDim.x) lS1[i] = bmS1[i];
    if (threadIdx.x == 0) lcnt = 0;
    __syncthreads();
    int tid0 = blockIdx.x * blockDim.x + threadIdx.x;
    int stride = gridDim.x * blockDim.x;
    int itersU = (nvec + stride - 1) / stride;
    for (int it = 0; it < itersU; ++it) {
        int v = tid0 + it * stride;
        if (v < nvec) {
            int4 d4 = dst4[v];
            int dd[4] = {d4.x, d4.y, d4.z, d4.w};
#pragma unroll
            for (int k = 0; k < 4; k++) {
                int d = dd[k];
                if ((lS1[d >> 5] >> (d & 31)) & 1u) {
                    int s = src[v * 4 + k];
                    uint bit = 1u << (s & 31);
                    uint old = atomicOr(&bmS0[s >> 5], bit);
                    if (!(old & bit)) deg[s] = 0;   // exactly-one first-toucher
                    int p = atomicAdd(&lcnt, 1);
                    if (p < LBUF) { lbs[p] = s; lbt[p] = d; }
                }
            }
        }
        __syncthreads();
        if (lcnt > FLUSH_THRESH) {
            int n = min(lcnt, LBUF);
            if (threadIdx.x == 0) gbase = atomicAdd(&cnts[3], n);
            __syncthreads();
            for (int i = threadIdx.x; i < n; i += blockDim.x) {
                int pos = gbase + i;
                if (pos < CAP_L1) { l1s[pos] = lbs[i]; l1t[pos] = lbt[i]; }
            }
            __syncthreads();
            if (threadIdx.x == 0) lcnt = 0;
        }
        __syncthreads();
    }
    int n = min(lcnt, LBUF);
    if (n > 0) {
        if (threadIdx.x == 0) gbase = atomicAdd(&cnts[3], n);
        __syncthreads();
        for (int i = threadIdx.x; i < n; i += blockDim.x) {
            int pos = gbase + i;
            if (pos < CAP_L1) { l1s[pos] = lbs[i]; l1t[pos] = lbt[i]; }
        }
    }
}

// ---- pass D: in-degree restricted to S0 (global bitmap) + default-output fill ----
__global__ __launch_bounds__(256) void k_passD(
        const int4* __restrict__ dst4, int nvec,
        const uint* __restrict__ bmS0, int* __restrict__ deg,
        vfloat4* __restrict__ out_score4, vfloat4* __restrict__ out_tgt4) {
    const vfloat4 zero = {0.f, 0.f, 0.f, 0.f};
    const vfloat4 neg1 = {-1.f, -1.f, -1.f, -1.f};
    int stride = gridDim.x * blockDim.x;
    for (int v = blockIdx.x * blockDim.x + threadIdx.x; v < nvec; v += stride) {
        int4 d4 = dst4[v];
        __builtin_nontemporal_store(zero, &out_score4[v]);
        __builtin_nontemporal_store(neg1, &out_tgt4[v]);
        int dd[4] = {d4.x, d4.y, d4.z, d4.w};
#pragma unroll
        for (int k = 0; k < 4; k++) {
            int d = dd[k];
            if ((bmS0[d >> 5] >> (d & 31)) & 1u) atomicAdd(&deg[d], 1);
        }
    }
}

// ---- conv1 accumulation over L1: acc1[d] += (x[s]@W1)*dinv[s] ----
__global__ void k_conv1(const int* __restrict__ cnts, const int* __restrict__ l1s,
                        const int* __restrict__ l1t, const float* __restrict__ x,
                        const float* __restrict__ W1, const int* __restrict__ deg,
                        float* __restrict__ acc1) {
    int n = cnts[3]; if (n > CAP_L1) n = CAP_L1;
    int stride = gridDim.x * blockDim.x;
    for (int j = blockIdx.x * blockDim.x + threadIdx.x; j < n; j += stride) {
        int s = l1s[j], d = l1t[j];
        float4 xv = *(const float4*)(x + (size_t)s * 4);
        float dis = rsqrtf((float)deg[s] + 1.0f);
        float o0 = (xv.x * W1[0] + xv.y * W1[4] + xv.z * W1[8]  + xv.w * W1[12]) * dis;
        float o1 = (xv.x * W1[1] + xv.y * W1[5] + xv.z * W1[9]  + xv.w * W1[13]) * dis;
        float o2 = (xv.x * W1[2] + xv.y * W1[6] + xv.z * W1[10] + xv.w * W1[14]) * dis;
        float o3 = (xv.x * W1[3] + xv.y * W1[7] + xv.z * W1[11] + xv.w * W1[15]) * dis;
        float* a = acc1 + (size_t)d * 4;
        atomicAdd(a + 0, o0); atomicAdd(a + 1, o1);
        atomicAdd(a + 2, o2); atomicAdd(a + 3, o3);
    }
}

// ---- tail: h1 over S1, conv2 over L2, z over T, softmax — one block ----
__global__ __launch_bounds__(1024) void k_tail(
        const int* __restrict__ cnts, const int* __restrict__ s1list,
        const int* __restrict__ l2s, const int* __restrict__ l2t,
        const int* __restrict__ le, const int* __restrict__ lt,
        const float* __restrict__ x, const float* __restrict__ W1,
        const float* __restrict__ b1, const float* __restrict__ W2,
        const float* __restrict__ b2, const float* __restrict__ Wr,
        const float* __restrict__ br, const int* __restrict__ deg,
        const float* __restrict__ acc1, float* __restrict__ acc2,
        float* __restrict__ gB, float* __restrict__ z,
        float* __restrict__ out_score, float* __restrict__ out_tgt) {
    int tid = threadIdx.x;
    // phase 1: h1 epilogue over S1 -> gB
    int n2 = cnts[2]; if (n2 > CAP_S1) n2 = CAP_S1;
    for (int j = tid; j < n2; j += blockDim.x) {
        int i = s1list[j];
        float di = rsqrtf((float)deg[i] + 1.0f);
        float4 xv = *(const float4*)(x + (size_t)i * 4);
        float4 a  = *(const float4*)(acc1 + (size_t)i * 4);
        float w0 = xv.x * W1[0] + xv.y * W1[4] + xv.z * W1[8]  + xv.w * W1[12];
        float w1 = xv.x * W1[1] + xv.y * W1[5] + xv.z * W1[9]  + xv.w * W1[13];
        float w2 = xv.x * W1[2] + xv.y * W1[6] + xv.z * W1[10] + xv.w * W1[14];
        float w3 = xv.x * W1[3] + xv.y * W1[7] + xv.z * W1[11] + xv.w * W1[15];
        float h0 = fmaxf((a.x + w0 * di) * di + b1[0], 0.f);
        float h1 = fmaxf((a.y + w1 * di) * di + b1[1], 0.f);
        float h2 = fmaxf((a.z + w2 * di) * di + b1[2], 0.f);
        float h3 = fmaxf((a.w + w3 * di) * di + b1[3], 0.f);
        float4 o;
        o.x = (h0 * W2[0] + h1 * W2[4] + h2 * W2[8]  + h3 * W2[12]) * di;
        o.y = (h0 * W2[1] + h1 * W2[5] + h2 * W2[9]  + h3 * W2[13]) * di;
        o.z = (h0 * W2[2] + h1 * W2[6] + h2 * W2[10] + h3 * W2[14]) * di;
        o.w = (h0 * W2[3] + h1 * W2[7] + h2 * W2[11] + h3 * W2[15]) * di;
        *(float4*)(gB + (size_t)i * 4) = o;
    }
    __syncthreads();
    // phase 2: conv2 over L2 -> acc2
    int nL2 = cnts[1]; if (nL2 > CAP_L2) nL2 = CAP_L2;
    for (int j = tid; j < nL2; j += blockDim.x) {
        int s = l2s[j], t = l2t[j];
        float4 g = *(const float4*)(gB + (size_t)s * 4);
        float* a = acc2 + (size_t)t * 4;
        atomicAdd(a + 0, g.x); atomicAdd(a + 1, g.y);
        atomicAdd(a + 2, g.z); atomicAdd(a + 3, g.w);
    }
    __syncthreads();
    // phase 3: z over incident targets (dup writes of same value are benign)
    int nI = cnts[0]; if (nI > CAP_I) nI = CAP_I;
    for (int j = tid; j < nI; j += blockDim.x) {
        int t = lt[j];
        float di = rsqrtf((float)deg[t] + 1.0f);
        float4 a = *(const float4*)(acc2 + (size_t)t * 4);
        float4 g = *(const float4*)(gB + (size_t)t * 4);
        float h0 = fmaxf((a.x + g.x) * di + b2[0], 0.f);
        float h1 = fmaxf((a.y + g.y) * di + b2[1], 0.f);
        float h2 = fmaxf((a.z + g.z) * di + b2[2], 0.f);
        float h3 = fmaxf((a.w + g.w) * di + b2[3], 0.f);
        z[t] = h0 * Wr[0] + h1 * Wr[1] + h2 * Wr[2] + h3 * Wr[3] + br[0];
    }
    __syncthreads();
    // phase 4: softmax (thread 0, n ~ 64)
    if (tid == 0) {
        float m = -3.402823466e+38f;
        for (int k = 0; k < nI; k++) m = fmaxf(m, z[lt[k]]);
        float ssum = 0.f;
        for (int k = 0; k < nI; k++) ssum += __expf(z[lt[k]] - m);
        float inv = (ssum > 0.f) ? 1.f / ssum : 0.f;
        for (int k = 0; k < nI; k++) {
            out_score[le[k]] = __expf(z[lt[k]] - m) * inv;
            out_tgt[le[k]]   = (float)lt[k];
        }
    }
}

extern "C" void kernel_launch(void* const* d_in, const int* in_sizes, int n_in,
                              void* d_out, int out_size, void* d_ws, size_t ws_size,
                              hipStream_t stream) {
    const float* x  = (const float*)d_in[0];
    const int*   ei = (const int*)d_in[1];
    const int*   nodep = (const int*)d_in[2];
    const float* W1 = (const float*)d_in[3];
    const float* b1 = (const float*)d_in[4];
    const float* W2 = (const float*)d_in[5];
    const float* b2 = (const float*)d_in[6];
    const float* Wr = (const float*)d_in[7];
    const float* br = (const float*)d_in[8];

    const int N = in_sizes[0] / 4;
    const int E = in_sizes[1] / 2;
    const int nvec = E / 4;
    const int NW = (N + 31) / 32;          // bitmap words (<= NWMAX for N<=501,760)
    const int* src = ei;
    const int* dst = ei + E;

    char* ws = (char*)d_ws;
    size_t off = 0;
    auto alloc = [&](size_t bytes) { char* p = ws + off; off = (off + bytes + 255) & ~(size_t)255; return p; };
    // ---- small zeroed region (bitmaps + cnts only; deg/acc first-touch zeroed) ----
    char* zero_base = ws;
    uint*  bmT    = (uint*) alloc((size_t)NW * 4);
    uint*  bmS1   = (uint*) alloc((size_t)NW * 4);
    uint*  bmS0   = (uint*) alloc((size_t)NW * 4);
    int*   cnts   = (int*)  alloc(256);                 // [0]=I [1]=L2 [2]=S1 [3]=L1
    size_t zero_len = off;
    // ---- non-zeroed ----
    int*   deg    = (int*)  alloc((size_t)N * 4);
    float* acc1   = (float*)alloc((size_t)N * 16);
    float* acc2   = (float*)alloc((size_t)N * 16);
    float* gB     = (float*)alloc((size_t)N * 16);
    float* z      = (float*)alloc((size_t)N * 4);
    int*   le     = (int*)  alloc((size_t)CAP_I * 4);
    int*   lt     = (int*)  alloc((size_t)CAP_I * 4);
    int*   s1list = (int*)  alloc((size_t)CAP_S1 * 4);
    int*   l2s    = (int*)  alloc((size_t)CAP_L2 * 4);
    int*   l2t    = (int*)  alloc((size_t)CAP_L2 * 4);
    int*   l1s    = (int*)  alloc((size_t)CAP_L1 * 4);
    int*   l1t    = (int*)  alloc((size_t)CAP_L1 * 4);

    float* out_score = (float*)d_out;
    float* out_tgt   = out_score + E;

    int edgeBlocksA = (nvec + 255) / 256;
    if (edgeBlocksA > 2048) edgeBlocksA = 2048;
    const int listBlocks = 256;

    (void)hipMemsetAsync(zero_base, 0, zero_len, stream);

    k_passA<<<edgeBlocksA, 256, 0, stream>>>((const int4*)src, (const int4*)dst, nvec, nodep,
                                             cnts, le, lt);
    k_markT<<<1, 256, 0, stream>>>(cnts, lt, bmT, bmS1, bmS0, cnts, s1list,
                                   deg, (float4*)acc1, (float4*)acc2);
    k_passB<<<512, 512, 0, stream>>>(src, (const int4*)dst, nvec, NW, bmT, bmS1, bmS0,
                                     cnts, l2s, l2t, s1list,
                                     deg, (float4*)acc1, (float4*)acc2);
    k_passC<<<512, 512, 0, stream>>>(src, (const int4*)dst, nvec, NW, bmS1, bmS0,
                                     cnts, l1s, l1t, deg);
    k_passD<<<2048, 256, 0, stream>>>((const int4*)dst, nvec, bmS0, deg,
                                      (vfloat4*)out_score, (vfloat4*)out_tgt);
    k_conv1<<<listBlocks, 256, 0, stream>>>(cnts, l1s, l1t, x, W1, deg, acc1);
    k_tail<<<1, 1024, 0, stream>>>(cnts, s1list, l2s, l2t, le, lt, x, W1, b1, W2, b2,
                                   Wr, br, deg, acc1, acc2, gB, z, out_score, out_tgt);
}

// Round 8
// 300.301 us; speedup vs baseline: 1.0973x; 1.0973x over previous
//
#include <hip/hip_runtime.h>

#define CAP_I   65536        // incident edges (expected ~64)
#define CAP_S1  (1 << 18)    // S1 nodes (expected ~2K)
#define CAP_L2  (1 << 20)    // edges into T (expected ~2K)
#define CAP_L1  (1 << 22)    // edges into S1 (expected ~64K)
#define LBUF    2560         // per-block LDS append buffer (entries)
#define NWMAX   15680        // bitmap words: supports N <= 501,760

typedef unsigned int uint;
typedef float vfloat4 __attribute__((ext_vector_type(4)));   // for nontemporal stores

// ---- pass A: stream src+dst, collect incident edges ----
__global__ void k_passA(const int4* __restrict__ src4, const int4* __restrict__ dst4, int nvec,
                        const int* __restrict__ nodep,
                        int* __restrict__ cnts, int* __restrict__ le, int* __restrict__ lt) {
    int node = *nodep;
    int stride = gridDim.x * blockDim.x;
    for (int v = blockIdx.x * blockDim.x + threadIdx.x; v < nvec; v += stride) {
        int4 s4 = src4[v];
        int4 d4 = dst4[v];
        int ss[4] = {s4.x, s4.y, s4.z, s4.w};
        int dd[4] = {d4.x, d4.y, d4.z, d4.w};
#pragma unroll
        for (int k = 0; k < 4; k++) {
            if (ss[k] == node || dd[k] == node) {
                int t = (ss[k] == node) ? dd[k] : ss[k];
                int pos = atomicAdd(&cnts[0], 1);
                if (pos < CAP_I) { le[pos] = v * 4 + k; lt[pos] = t; }
            }
        }
    }
}

// ---- mark T, seed S1/S0 with T; first-touch zero deg/acc1/acc2 ----
__global__ void k_markT(const int* __restrict__ cnts, const int* __restrict__ lt,
                        uint* __restrict__ bmT, uint* __restrict__ bmS1,
                        uint* __restrict__ bmS0,
                        int* __restrict__ cnts_w, int* __restrict__ s1list,
                        int* __restrict__ deg, float4* __restrict__ acc1,
                        float4* __restrict__ acc2) {
    int n = cnts[0]; if (n > CAP_I) n = CAP_I;
    const float4 z4 = make_float4(0.f, 0.f, 0.f, 0.f);
    for (int i = threadIdx.x; i < n; i += blockDim.x) {
        int t = lt[i];
        uint bit = 1u << (t & 31);
        atomicOr(&bmT[t >> 5], bit);
        uint old = atomicOr(&bmS1[t >> 5], bit);
        if (!(old & bit)) {
            atomicOr(&bmS0[t >> 5], bit);
            deg[t] = 0; acc1[t] = z4; acc2[t] = z4;
            int p = atomicAdd(&cnts_w[2], 1);
            if (p < CAP_S1) s1list[p] = t;
        }
    }
}

// ---- pass B: dst in T -> L2 edges, srcs -> S1. Barrier-free scan; LDS append
//      with rare direct-global spill; one final flush. ----
__global__ __launch_bounds__(512) void k_passB(
        const int* __restrict__ src, const int4* __restrict__ dst4, int nvec, int NW,
        const uint* __restrict__ bmT, uint* __restrict__ bmS1, uint* __restrict__ bmS0,
        int* __restrict__ cnts, int* __restrict__ l2s, int* __restrict__ l2t,
        int* __restrict__ s1list,
        int* __restrict__ deg, float4* __restrict__ acc1, float4* __restrict__ acc2) {
    __shared__ uint lT[NWMAX];
    __shared__ int bes[LBUF], bet[LBUF], bs1[LBUF];
    __shared__ int lcE, lcS, gbE, gbS;
    for (int i = threadIdx.x; i < NW; i += blockDim.x) lT[i] = bmT[i];
    if (threadIdx.x == 0) { lcE = 0; lcS = 0; }
    __syncthreads();
    const float4 z4 = make_float4(0.f, 0.f, 0.f, 0.f);
    int stride = gridDim.x * blockDim.x;
    for (int v = blockIdx.x * blockDim.x + threadIdx.x; v < nvec; v += stride) {
        int4 d4 = dst4[v];
        int dd[4] = {d4.x, d4.y, d4.z, d4.w};
#pragma unroll
        for (int k = 0; k < 4; k++) {
            int d = dd[k];
            if ((lT[d >> 5] >> (d & 31)) & 1u) {
                int s = src[v * 4 + k];
                int p = atomicAdd(&lcE, 1);
                if (p < LBUF) { bes[p] = s; bet[p] = d; }
                else {  // rare spill: exact, order-independent
                    int g = atomicAdd(&cnts[1], 1);
                    if (g < CAP_L2) { l2s[g] = s; l2t[g] = d; }
                }
                uint bit = 1u << (s & 31);
                uint old = atomicOr(&bmS1[s >> 5], bit);
                if (!(old & bit)) {
                    atomicOr(&bmS0[s >> 5], bit);
                    deg[s] = 0; acc1[s] = z4; acc2[s] = z4;
                    int q = atomicAdd(&lcS, 1);
                    if (q < LBUF) bs1[q] = s;
                    else {
                        int g = atomicAdd(&cnts[2], 1);
                        if (g < CAP_S1) s1list[g] = s;
                    }
                }
            }
        }
    }
    __syncthreads();
    int nE = min(lcE, LBUF), nS = min(lcS, LBUF);
    if (threadIdx.x == 0) {
        gbE = (nE > 0) ? atomicAdd(&cnts[1], nE) : 0;
        gbS = (nS > 0) ? atomicAdd(&cnts[2], nS) : 0;
    }
    __syncthreads();
    for (int i = threadIdx.x; i < nE; i += blockDim.x) {
        int pos = gbE + i;
        if (pos < CAP_L2) { l2s[pos] = bes[i]; l2t[pos] = bet[i]; }
    }
    for (int i = threadIdx.x; i < nS; i += blockDim.x) {
        int pos = gbS + i;
        if (pos < CAP_S1) s1list[pos] = bs1[i];
    }
}

// ---- pass C: dst in S1 -> L1 edges, srcs -> S0. Barrier-free scan. ----
__global__ __launch_bounds__(512) void k_passC(
        const int* __restrict__ src, const int4* __restrict__ dst4, int nvec, int NW,
        const uint* __restrict__ bmS1, uint* __restrict__ bmS0,
        int* __restrict__ cnts, int* __restrict__ l1s, int* __restrict__ l1t,
        int* __restrict__ deg) {
    __shared__ uint lS1[NWMAX];
    __shared__ int lbs[LBUF], lbt[LBUF];
    __shared__ int lcnt, gbase;
    for (int i = threadIdx.x; i < NW; i += blockDim.x) lS1[i] = bmS1[i];
    if (threadIdx.x == 0) lcnt = 0;
    __syncthreads();
    int stride = gridDim.x * blockDim.x;
    for (int v = blockIdx.x * blockDim.x + threadIdx.x; v < nvec; v += stride) {
        int4 d4 = dst4[v];
        int dd[4] = {d4.x, d4.y, d4.z, d4.w};
#pragma unroll
        for (int k = 0; k < 4; k++) {
            int d = dd[k];
            if ((lS1[d >> 5] >> (d & 31)) & 1u) {
                int s = src[v * 4 + k];
                uint bit = 1u << (s & 31);
                uint old = atomicOr(&bmS0[s >> 5], bit);
                if (!(old & bit)) deg[s] = 0;   // exactly-one first-toucher
                int p = atomicAdd(&lcnt, 1);
                if (p < LBUF) { lbs[p] = s; lbt[p] = d; }
                else {  // rare spill
                    int g = atomicAdd(&cnts[3], 1);
                    if (g < CAP_L1) { l1s[g] = s; l1t[g] = d; }
                }
            }
        }
    }
    __syncthreads();
    int n = min(lcnt, LBUF);
    if (threadIdx.x == 0) gbase = (n > 0) ? atomicAdd(&cnts[3], n) : 0;
    __syncthreads();
    for (int i = threadIdx.x; i < n; i += blockDim.x) {
        int pos = gbase + i;
        if (pos < CAP_L1) { l1s[pos] = lbs[i]; l1t[pos] = lbt[i]; }
    }
}

// ---- pass D: in-degree restricted to S0 (global bitmap) + default-output fill ----
__global__ __launch_bounds__(256) void k_passD(
        const int4* __restrict__ dst4, int nvec,
        const uint* __restrict__ bmS0, int* __restrict__ deg,
        vfloat4* __restrict__ out_score4, vfloat4* __restrict__ out_tgt4) {
    const vfloat4 zero = {0.f, 0.f, 0.f, 0.f};
    const vfloat4 neg1 = {-1.f, -1.f, -1.f, -1.f};
    int stride = gridDim.x * blockDim.x;
    for (int v = blockIdx.x * blockDim.x + threadIdx.x; v < nvec; v += stride) {
        int4 d4 = dst4[v];
        __builtin_nontemporal_store(zero, &out_score4[v]);
        __builtin_nontemporal_store(neg1, &out_tgt4[v]);
        int dd[4] = {d4.x, d4.y, d4.z, d4.w};
#pragma unroll
        for (int k = 0; k < 4; k++) {
            int d = dd[k];
            if ((bmS0[d >> 5] >> (d & 31)) & 1u) atomicAdd(&deg[d], 1);
        }
    }
}

// ---- conv1 accumulation over L1: acc1[d] += (x[s]@W1)*dinv[s] ----
__global__ void k_conv1(const int* __restrict__ cnts, const int* __restrict__ l1s,
                        const int* __restrict__ l1t, const float* __restrict__ x,
                        const float* __restrict__ W1, const int* __restrict__ deg,
                        float* __restrict__ acc1) {
    int n = cnts[3]; if (n > CAP_L1) n = CAP_L1;
    int stride = gridDim.x * blockDim.x;
    for (int j = blockIdx.x * blockDim.x + threadIdx.x; j < n; j += stride) {
        int s = l1s[j], d = l1t[j];
        float4 xv = *(const float4*)(x + (size_t)s * 4);
        float dis = rsqrtf((float)deg[s] + 1.0f);
        float o0 = (xv.x * W1[0] + xv.y * W1[4] + xv.z * W1[8]  + xv.w * W1[12]) * dis;
        float o1 = (xv.x * W1[1] + xv.y * W1[5] + xv.z * W1[9]  + xv.w * W1[13]) * dis;
        float o2 = (xv.x * W1[2] + xv.y * W1[6] + xv.z * W1[10] + xv.w * W1[14]) * dis;
        float o3 = (xv.x * W1[3] + xv.y * W1[7] + xv.z * W1[11] + xv.w * W1[15]) * dis;
        float* a = acc1 + (size_t)d * 4;
        atomicAdd(a + 0, o0); atomicAdd(a + 1, o1);
        atomicAdd(a + 2, o2); atomicAdd(a + 3, o3);
    }
}

// ---- tail: h1 over S1, conv2 over L2, z over T, softmax — one block ----
__global__ __launch_bounds__(1024) void k_tail(
        const int* __restrict__ cnts, const int* __restrict__ s1list,
        const int* __restrict__ l2s, const int* __restrict__ l2t,
        const int* __restrict__ le, const int* __restrict__ lt,
        const float* __restrict__ x, const float* __restrict__ W1,
        const float* __restrict__ b1, const float* __restrict__ W2,
        const float* __restrict__ b2, const float* __restrict__ Wr,
        const float* __restrict__ br, const int* __restrict__ deg,
        const float* __restrict__ acc1, float* __restrict__ acc2,
        float* __restrict__ gB, float* __restrict__ z,
        float* __restrict__ out_score, float* __restrict__ out_tgt) {
    int tid = threadIdx.x;
    // phase 1: h1 epilogue over S1 -> gB
    int n2 = cnts[2]; if (n2 > CAP_S1) n2 = CAP_S1;
    for (int j = tid; j < n2; j += blockDim.x) {
        int i = s1list[j];
        float di = rsqrtf((float)deg[i] + 1.0f);
        float4 xv = *(const float4*)(x + (size_t)i * 4);
        float4 a  = *(const float4*)(acc1 + (size_t)i * 4);
        float w0 = xv.x * W1[0] + xv.y * W1[4] + xv.z * W1[8]  + xv.w * W1[12];
        float w1 = xv.x * W1[1] + xv.y * W1[5] + xv.z * W1[9]  + xv.w * W1[13];
        float w2 = xv.x * W1[2] + xv.y * W1[6] + xv.z * W1[10] + xv.w * W1[14];
        float w3 = xv.x * W1[3] + xv.y * W1[7] + xv.z * W1[11] + xv.w * W1[15];
        float h0 = fmaxf((a.x + w0 * di) * di + b1[0], 0.f);
        float h1 = fmaxf((a.y + w1 * di) * di + b1[1], 0.f);
        float h2 = fmaxf((a.z + w2 * di) * di + b1[2], 0.f);
        float h3 = fmaxf((a.w + w3 * di) * di + b1[3], 0.f);
        float4 o;
        o.x = (h0 * W2[0] + h1 * W2[4] + h2 * W2[8]  + h3 * W2[12]) * di;
        o.y = (h0 * W2[1] + h1 * W2[5] + h2 * W2[9]  + h3 * W2[13]) * di;
        o.z = (h0 * W2[2] + h1 * W2[6] + h2 * W2[10] + h3 * W2[14]) * di;
        o.w = (h0 * W2[3] + h1 * W2[7] + h2 * W2[11] + h3 * W2[15]) * di;
        *(float4*)(gB + (size_t)i * 4) = o;
    }
    __syncthreads();
    // phase 2: conv2 over L2 -> acc2
    int nL2 = cnts[1]; if (nL2 > CAP_L2) nL2 = CAP_L2;
    for (int j = tid; j < nL2; j += blockDim.x) {
        int s = l2s[j], t = l2t[j];
        float4 g = *(const float4*)(gB + (size_t)s * 4);
        float* a = acc2 + (size_t)t * 4;
        atomicAdd(a + 0, g.x); atomicAdd(a + 1, g.y);
        atomicAdd(a + 2, g.z); atomicAdd(a + 3, g.w);
    }
    __syncthreads();
    // phase 3: z over incident targets (dup writes of same value are benign)
    int nI = cnts[0]; if (nI > CAP_I) nI = CAP_I;
    for (int j = tid; j < nI; j += blockDim.x) {
        int t = lt[j];
        float di = rsqrtf((float)deg[t] + 1.0f);
        float4 a = *(const float4*)(acc2 + (size_t)t * 4);
        float4 g = *(const float4*)(gB + (size_t)t * 4);
        float h0 = fmaxf((a.x + g.x) * di + b2[0], 0.f);
        float h1 = fmaxf((a.y + g.y) * di + b2[1], 0.f);
        float h2 = fmaxf((a.z + g.z) * di + b2[2], 0.f);
        float h3 = fmaxf((a.w + g.w) * di + b2[3], 0.f);
        z[t] = h0 * Wr[0] + h1 * Wr[1] + h2 * Wr[2] + h3 * Wr[3] + br[0];
    }
    __syncthreads();
    // phase 4: softmax (thread 0, n ~ 64)
    if (tid == 0) {
        float m = -3.402823466e+38f;
        for (int k = 0; k < nI; k++) m = fmaxf(m, z[lt[k]]);
        float ssum = 0.f;
        for (int k = 0; k < nI; k++) ssum += __expf(z[lt[k]] - m);
        float inv = (ssum > 0.f) ? 1.f / ssum : 0.f;
        for (int k = 0; k < nI; k++) {
            out_score[le[k]] = __expf(z[lt[k]] - m) * inv;
            out_tgt[le[k]]   = (float)lt[k];
        }
    }
}

extern "C" void kernel_launch(void* const* d_in, const int* in_sizes, int n_in,
                              void* d_out, int out_size, void* d_ws, size_t ws_size,
                              hipStream_t stream) {
    const float* x  = (const float*)d_in[0];
    const int*   ei = (const int*)d_in[1];
    const int*   nodep = (const int*)d_in[2];
    const float* W1 = (const float*)d_in[3];
    const float* b1 = (const float*)d_in[4];
    const float* W2 = (const float*)d_in[5];
    const float* b2 = (const float*)d_in[6];
    const float* Wr = (const float*)d_in[7];
    const float* br = (const float*)d_in[8];

    const int N = in_sizes[0] / 4;
    const int E = in_sizes[1] / 2;
    const int nvec = E / 4;
    const int NW = (N + 31) / 32;          // bitmap words (<= NWMAX for N<=501,760)
    const int* src = ei;
    const int* dst = ei + E;

    char* ws = (char*)d_ws;
    size_t off = 0;
    auto alloc = [&](size_t bytes) { char* p = ws + off; off = (off + bytes + 255) & ~(size_t)255; return p; };
    // ---- small zeroed region (bitmaps + cnts only; deg/acc first-touch zeroed) ----
    char* zero_base = ws;
    uint*  bmT    = (uint*) alloc((size_t)NW * 4);
    uint*  bmS1   = (uint*) alloc((size_t)NW * 4);
    uint*  bmS0   = (uint*) alloc((size_t)NW * 4);
    int*   cnts   = (int*)  alloc(256);                 // [0]=I [1]=L2 [2]=S1 [3]=L1
    size_t zero_len = off;
    // ---- non-zeroed ----
    int*   deg    = (int*)  alloc((size_t)N * 4);
    float* acc1   = (float*)alloc((size_t)N * 16);
    float* acc2   = (float*)alloc((size_t)N * 16);
    float* gB     = (float*)alloc((size_t)N * 16);
    float* z      = (float*)alloc((size_t)N * 4);
    int*   le     = (int*)  alloc((size_t)CAP_I * 4);
    int*   lt     = (int*)  alloc((size_t)CAP_I * 4);
    int*   s1list = (int*)  alloc((size_t)CAP_S1 * 4);
    int*   l2s    = (int*)  alloc((size_t)CAP_L2 * 4);
    int*   l2t    = (int*)  alloc((size_t)CAP_L2 * 4);
    int*   l1s    = (int*)  alloc((size_t)CAP_L1 * 4);
    int*   l1t    = (int*)  alloc((size_t)CAP_L1 * 4);

    float* out_score = (float*)d_out;
    float* out_tgt   = out_score + E;

    int edgeBlocksA = (nvec + 255) / 256;
    if (edgeBlocksA > 2048) edgeBlocksA = 2048;

    (void)hipMemsetAsync(zero_base, 0, zero_len, stream);

    k_passA<<<edgeBlocksA, 256, 0, stream>>>((const int4*)src, (const int4*)dst, nvec, nodep,
                                             cnts, le, lt);
    k_markT<<<1, 256, 0, stream>>>(cnts, lt, bmT, bmS1, bmS0, cnts, s1list,
                                   deg, (float4*)acc1, (float4*)acc2);
    k_passB<<<512, 512, 0, stream>>>(src, (const int4*)dst, nvec, NW, bmT, bmS1, bmS0,
                                     cnts, l2s, l2t, s1list,
                                     deg, (float4*)acc1, (float4*)acc2);
    k_passC<<<512, 512, 0, stream>>>(src, (const int4*)dst, nvec, NW, bmS1, bmS0,
                                     cnts, l1s, l1t, deg);
    k_passD<<<2048, 256, 0, stream>>>((const int4*)dst, nvec, bmS0, deg,
                                      (vfloat4*)out_score, (vfloat4*)out_tgt);
    k_conv1<<<256, 256, 0, stream>>>(cnts, l1s, l1t, x, W1, deg, acc1);
    k_tail<<<1, 1024, 0, stream>>>(cnts, s1list, l2s, l2t, le, lt, x, W1, b1, W2, b2,
                                   Wr, br, deg, acc1, acc2, gB, z, out_score, out_tgt);
}

// Round 9
// 281.261 us; speedup vs baseline: 1.1716x; 1.0677x over previous
//
#include <hip/hip_runtime.h>

#define CAP_I   65536        // incident edges (expected ~64)
#define CAP_S1  (1 << 18)    // S1 nodes (expected ~2K)
#define CAP_L2  (1 << 20)    // edges into T (expected ~2K)
#define CAP_L1  (1 << 22)    // edges into S1 (expected ~64K)
#define LBUF_B  512          // passB per-block LDS append buffer
#define LBUF_C  1024         // passC per-block LDS append buffer
#define CBT_W   977          // coarse-T words: ceil(N/512), buckets of 16 nodes
#define CBS_W   1954         // coarse-S1 words: ceil(N/256), buckets of 8 nodes

typedef unsigned int uint;
typedef float vfloat4 __attribute__((ext_vector_type(4)));   // for nontemporal stores

// ---- pass A: stream src+dst, collect incident edges; inline T/S1/S0 marking ----
__global__ void k_passA(const int4* __restrict__ src4, const int4* __restrict__ dst4, int nvec,
                        const int* __restrict__ nodep,
                        int* __restrict__ cnts, int* __restrict__ le, int* __restrict__ lt,
                        uint* __restrict__ bmT, uint* __restrict__ bmS1,
                        uint* __restrict__ bmS0,
                        uint* __restrict__ cbmT, uint* __restrict__ cbmS1,
                        int* __restrict__ s1list,
                        int* __restrict__ deg, float4* __restrict__ acc1,
                        float4* __restrict__ acc2) {
    const float4 z4 = make_float4(0.f, 0.f, 0.f, 0.f);
    int node = *nodep;
    int stride = gridDim.x * blockDim.x;
    for (int v = blockIdx.x * blockDim.x + threadIdx.x; v < nvec; v += stride) {
        int4 s4 = src4[v];
        int4 d4 = dst4[v];
        int ss[4] = {s4.x, s4.y, s4.z, s4.w};
        int dd[4] = {d4.x, d4.y, d4.z, d4.w};
#pragma unroll
        for (int k = 0; k < 4; k++) {
            if (ss[k] == node || dd[k] == node) {
                int t = (ss[k] == node) ? dd[k] : ss[k];
                int pos = atomicAdd(&cnts[0], 1);
                if (pos < CAP_I) { le[pos] = v * 4 + k; lt[pos] = t; }
                uint bit = 1u << (t & 31);
                atomicOr(&bmT[t >> 5], bit);
                atomicOr(&cbmT[t >> 9], 1u << ((t >> 4) & 31));
                uint old = atomicOr(&bmS1[t >> 5], bit);
                if (!(old & bit)) {                       // first-touch into S1
                    atomicOr(&bmS0[t >> 5], bit);
                    atomicOr(&cbmS1[t >> 8], 1u << ((t >> 3) & 31));
                    deg[t] = 0; acc1[t] = z4; acc2[t] = z4;
                    int p = atomicAdd(&cnts[2], 1);
                    if (p < CAP_S1) s1list[p] = t;
                }
            }
        }
    }
}

// ---- pass B: coarse-T LDS filter; fine probe global bmT; hits -> L2 list, srcs -> S1 ----
__global__ __launch_bounds__(256) void k_passB(
        const int* __restrict__ src, const int4* __restrict__ dst4, int nvec,
        const uint* __restrict__ cbmT, const uint* __restrict__ bmT,
        uint* __restrict__ bmS1, uint* __restrict__ bmS0, uint* __restrict__ cbmS1,
        int* __restrict__ cnts, int* __restrict__ l2s, int* __restrict__ l2t,
        int* __restrict__ s1list,
        int* __restrict__ deg, float4* __restrict__ acc1, float4* __restrict__ acc2) {
    __shared__ uint lcb[CBT_W];
    __shared__ int bes[LBUF_B], bet[LBUF_B], bs1[LBUF_B];
    __shared__ int lcE, lcS, gbE, gbS;
    for (int i = threadIdx.x; i < CBT_W; i += blockDim.x) lcb[i] = cbmT[i];
    if (threadIdx.x == 0) { lcE = 0; lcS = 0; }
    __syncthreads();
    const float4 z4 = make_float4(0.f, 0.f, 0.f, 0.f);
    int stride = gridDim.x * blockDim.x;
    for (int v = blockIdx.x * blockDim.x + threadIdx.x; v < nvec; v += stride) {
        int4 d4 = dst4[v];
        int dd[4] = {d4.x, d4.y, d4.z, d4.w};
#pragma unroll
        for (int k = 0; k < 4; k++) {
            int d = dd[k];
            if ((lcb[d >> 9] >> ((d >> 4) & 31)) & 1u) {        // coarse (0.2% pass)
                if ((bmT[d >> 5] >> (d & 31)) & 1u) {           // exact
                    int s = src[v * 4 + k];
                    int p = atomicAdd(&lcE, 1);
                    if (p < LBUF_B) { bes[p] = s; bet[p] = d; }
                    else { int g = atomicAdd(&cnts[1], 1);
                           if (g < CAP_L2) { l2s[g] = s; l2t[g] = d; } }
                    uint bit = 1u << (s & 31);
                    uint old = atomicOr(&bmS1[s >> 5], bit);
                    if (!(old & bit)) {
                        atomicOr(&bmS0[s >> 5], bit);
                        atomicOr(&cbmS1[s >> 8], 1u << ((s >> 3) & 31));
                        deg[s] = 0; acc1[s] = z4; acc2[s] = z4;
                        int q = atomicAdd(&lcS, 1);
                        if (q < LBUF_B) bs1[q] = s;
                        else { int g = atomicAdd(&cnts[2], 1);
                               if (g < CAP_S1) s1list[g] = s; }
                    }
                }
            }
        }
    }
    __syncthreads();
    int nE = min(lcE, LBUF_B), nS = min(lcS, LBUF_B);
    if (threadIdx.x == 0) {
        gbE = (nE > 0) ? atomicAdd(&cnts[1], nE) : 0;
        gbS = (nS > 0) ? atomicAdd(&cnts[2], nS) : 0;
    }
    __syncthreads();
    for (int i = threadIdx.x; i < nE; i += blockDim.x) {
        int pos = gbE + i;
        if (pos < CAP_L2) { l2s[pos] = bes[i]; l2t[pos] = bet[i]; }
    }
    for (int i = threadIdx.x; i < nS; i += blockDim.x) {
        int pos = gbS + i;
        if (pos < CAP_S1) s1list[pos] = bs1[i];
    }
}

// ---- pass C: coarse-S1 LDS filter; fine probe global bmS1; hits -> L1 list, srcs -> S0 ----
__global__ __launch_bounds__(256) void k_passC(
        const int* __restrict__ src, const int4* __restrict__ dst4, int nvec,
        const uint* __restrict__ cbmS1, const uint* __restrict__ bmS1,
        uint* __restrict__ bmS0,
        int* __restrict__ cnts, int* __restrict__ l1s, int* __restrict__ l1t,
        int* __restrict__ deg) {
    __shared__ uint lcb[CBS_W];
    __shared__ int lbs[LBUF_C], lbt[LBUF_C];
    __shared__ int lcnt, gbase;
    for (int i = threadIdx.x; i < CBS_W; i += blockDim.x) lcb[i] = cbmS1[i];
    if (threadIdx.x == 0) lcnt = 0;
    __syncthreads();
    int stride = gridDim.x * blockDim.x;
    for (int v = blockIdx.x * blockDim.x + threadIdx.x; v < nvec; v += stride) {
        int4 d4 = dst4[v];
        int dd[4] = {d4.x, d4.y, d4.z, d4.w};
#pragma unroll
        for (int k = 0; k < 4; k++) {
            int d = dd[k];
            if ((lcb[d >> 8] >> ((d >> 3) & 31)) & 1u) {        // coarse (~3% pass)
                if ((bmS1[d >> 5] >> (d & 31)) & 1u) {          // exact
                    int s = src[v * 4 + k];
                    uint bit = 1u << (s & 31);
                    uint old = atomicOr(&bmS0[s >> 5], bit);
                    if (!(old & bit)) deg[s] = 0;   // exactly-one first-toucher
                    int p = atomicAdd(&lcnt, 1);
                    if (p < LBUF_C) { lbs[p] = s; lbt[p] = d; }
                    else { int g = atomicAdd(&cnts[3], 1);
                           if (g < CAP_L1) { l1s[g] = s; l1t[g] = d; } }
                }
            }
        }
    }
    __syncthreads();
    int n = min(lcnt, LBUF_C);
    if (threadIdx.x == 0) gbase = (n > 0) ? atomicAdd(&cnts[3], n) : 0;
    __syncthreads();
    for (int i = threadIdx.x; i < n; i += blockDim.x) {
        int pos = gbase + i;
        if (pos < CAP_L1) { l1s[pos] = lbs[i]; l1t[pos] = lbt[i]; }
    }
}

// ---- pass D: in-degree restricted to S0 (global bitmap) + default-output fill ----
__global__ __launch_bounds__(256) void k_passD(
        const int4* __restrict__ dst4, int nvec,
        const uint* __restrict__ bmS0, int* __restrict__ deg,
        vfloat4* __restrict__ out_score4, vfloat4* __restrict__ out_tgt4) {
    const vfloat4 zero = {0.f, 0.f, 0.f, 0.f};
    const vfloat4 neg1 = {-1.f, -1.f, -1.f, -1.f};
    int stride = gridDim.x * blockDim.x;
    for (int v = blockIdx.x * blockDim.x + threadIdx.x; v < nvec; v += stride) {
        int4 d4 = dst4[v];
        __builtin_nontemporal_store(zero, &out_score4[v]);
        __builtin_nontemporal_store(neg1, &out_tgt4[v]);
        int dd[4] = {d4.x, d4.y, d4.z, d4.w};
#pragma unroll
        for (int k = 0; k < 4; k++) {
            int d = dd[k];
            if ((bmS0[d >> 5] >> (d & 31)) & 1u) atomicAdd(&deg[d], 1);
        }
    }
}

// ---- conv1 accumulation over L1: acc1[d] += (x[s]@W1)*dinv[s] ----
__global__ void k_conv1(const int* __restrict__ cnts, const int* __restrict__ l1s,
                        const int* __restrict__ l1t, const float* __restrict__ x,
                        const float* __restrict__ W1, const int* __restrict__ deg,
                        float* __restrict__ acc1) {
    int n = cnts[3]; if (n > CAP_L1) n = CAP_L1;
    int stride = gridDim.x * blockDim.x;
    for (int j = blockIdx.x * blockDim.x + threadIdx.x; j < n; j += stride) {
        int s = l1s[j], d = l1t[j];
        float4 xv = *(const float4*)(x + (size_t)s * 4);
        float dis = rsqrtf((float)deg[s] + 1.0f);
        float o0 = (xv.x * W1[0] + xv.y * W1[4] + xv.z * W1[8]  + xv.w * W1[12]) * dis;
        float o1 = (xv.x * W1[1] + xv.y * W1[5] + xv.z * W1[9]  + xv.w * W1[13]) * dis;
        float o2 = (xv.x * W1[2] + xv.y * W1[6] + xv.z * W1[10] + xv.w * W1[14]) * dis;
        float o3 = (xv.x * W1[3] + xv.y * W1[7] + xv.z * W1[11] + xv.w * W1[15]) * dis;
        float* a = acc1 + (size_t)d * 4;
        atomicAdd(a + 0, o0); atomicAdd(a + 1, o1);
        atomicAdd(a + 2, o2); atomicAdd(a + 3, o3);
    }
}

// ---- tail: h1 over S1, conv2 over L2, z over T, softmax — one block ----
__global__ __launch_bounds__(1024) void k_tail(
        const int* __restrict__ cnts, const int* __restrict__ s1list,
        const int* __restrict__ l2s, const int* __restrict__ l2t,
        const int* __restrict__ le, const int* __restrict__ lt,
        const float* __restrict__ x, const float* __restrict__ W1,
        const float* __restrict__ b1, const float* __restrict__ W2,
        const float* __restrict__ b2, const float* __restrict__ Wr,
        const float* __restrict__ br, const int* __restrict__ deg,
        const float* __restrict__ acc1, float* __restrict__ acc2,
        float* __restrict__ gB, float* __restrict__ z,
        float* __restrict__ out_score, float* __restrict__ out_tgt) {
    int tid = threadIdx.x;
    // phase 1: h1 epilogue over S1 -> gB
    int n2 = cnts[2]; if (n2 > CAP_S1) n2 = CAP_S1;
    for (int j = tid; j < n2; j += blockDim.x) {
        int i = s1list[j];
        float di = rsqrtf((float)deg[i] + 1.0f);
        float4 xv = *(const float4*)(x + (size_t)i * 4);
        float4 a  = *(const float4*)(acc1 + (size_t)i * 4);
        float w0 = xv.x * W1[0] + xv.y * W1[4] + xv.z * W1[8]  + xv.w * W1[12];
        float w1 = xv.x * W1[1] + xv.y * W1[5] + xv.z * W1[9]  + xv.w * W1[13];
        float w2 = xv.x * W1[2] + xv.y * W1[6] + xv.z * W1[10] + xv.w * W1[14];
        float w3 = xv.x * W1[3] + xv.y * W1[7] + xv.z * W1[11] + xv.w * W1[15];
        float h0 = fmaxf((a.x + w0 * di) * di + b1[0], 0.f);
        float h1 = fmaxf((a.y + w1 * di) * di + b1[1], 0.f);
        float h2 = fmaxf((a.z + w2 * di) * di + b1[2], 0.f);
        float h3 = fmaxf((a.w + w3 * di) * di + b1[3], 0.f);
        float4 o;
        o.x = (h0 * W2[0] + h1 * W2[4] + h2 * W2[8]  + h3 * W2[12]) * di;
        o.y = (h0 * W2[1] + h1 * W2[5] + h2 * W2[9]  + h3 * W2[13]) * di;
        o.z = (h0 * W2[2] + h1 * W2[6] + h2 * W2[10] + h3 * W2[14]) * di;
        o.w = (h0 * W2[3] + h1 * W2[7] + h2 * W2[11] + h3 * W2[15]) * di;
        *(float4*)(gB + (size_t)i * 4) = o;
    }
    __syncthreads();
    // phase 2: conv2 over L2 -> acc2
    int nL2 = cnts[1]; if (nL2 > CAP_L2) nL2 = CAP_L2;
    for (int j = tid; j < nL2; j += blockDim.x) {
        int s = l2s[j], t = l2t[j];
        float4 g = *(const float4*)(gB + (size_t)s * 4);
        float* a = acc2 + (size_t)t * 4;
        atomicAdd(a + 0, g.x); atomicAdd(a + 1, g.y);
        atomicAdd(a + 2, g.z); atomicAdd(a + 3, g.w);
    }
    __syncthreads();
    // phase 3: z over incident targets (dup writes of same value are benign)
    int nI = cnts[0]; if (nI > CAP_I) nI = CAP_I;
    for (int j = tid; j < nI; j += blockDim.x) {
        int t = lt[j];
        float di = rsqrtf((float)deg[t] + 1.0f);
        float4 a = *(const float4*)(acc2 + (size_t)t * 4);
        float4 g = *(const float4*)(gB + (size_t)t * 4);
        float h0 = fmaxf((a.x + g.x) * di + b2[0], 0.f);
        float h1 = fmaxf((a.y + g.y) * di + b2[1], 0.f);
        float h2 = fmaxf((a.z + g.z) * di + b2[2], 0.f);
        float h3 = fmaxf((a.w + g.w) * di + b2[3], 0.f);
        z[t] = h0 * Wr[0] + h1 * Wr[1] + h2 * Wr[2] + h3 * Wr[3] + br[0];
    }
    __syncthreads();
    // phase 4: softmax (thread 0, n ~ 64)
    if (tid == 0) {
        float m = -3.402823466e+38f;
        for (int k = 0; k < nI; k++) m = fmaxf(m, z[lt[k]]);
        float ssum = 0.f;
        for (int k = 0; k < nI; k++) ssum += __expf(z[lt[k]] - m);
        float inv = (ssum > 0.f) ? 1.f / ssum : 0.f;
        for (int k = 0; k < nI; k++) {
            out_score[le[k]] = __expf(z[lt[k]] - m) * inv;
            out_tgt[le[k]]   = (float)lt[k];
        }
    }
}

extern "C" void kernel_launch(void* const* d_in, const int* in_sizes, int n_in,
                              void* d_out, int out_size, void* d_ws, size_t ws_size,
                              hipStream_t stream) {
    const float* x  = (const float*)d_in[0];
    const int*   ei = (const int*)d_in[1];
    const int*   nodep = (const int*)d_in[2];
    const float* W1 = (const float*)d_in[3];
    const float* b1 = (const float*)d_in[4];
    const float* W2 = (const float*)d_in[5];
    const float* b2 = (const float*)d_in[6];
    const float* Wr = (const float*)d_in[7];
    const float* br = (const float*)d_in[8];

    const int N = in_sizes[0] / 4;
    const int E = in_sizes[1] / 2;
    const int nvec = E / 4;
    const int NW = (N + 31) / 32;
    const int* src = ei;
    const int* dst = ei + E;

    char* ws = (char*)d_ws;
    size_t off = 0;
    auto alloc = [&](size_t bytes) { char* p = ws + off; off = (off + bytes + 255) & ~(size_t)255; return p; };
    // ---- small zeroed region (exact+coarse bitmaps + cnts; deg/acc first-touch zeroed) ----
    char* zero_base = ws;
    uint*  bmT    = (uint*) alloc((size_t)NW * 4);
    uint*  bmS1   = (uint*) alloc((size_t)NW * 4);
    uint*  bmS0   = (uint*) alloc((size_t)NW * 4);
    uint*  cbmT   = (uint*) alloc((size_t)CBT_W * 4);
    uint*  cbmS1  = (uint*) alloc((size_t)CBS_W * 4);
    int*   cnts   = (int*)  alloc(256);                 // [0]=I [1]=L2 [2]=S1 [3]=L1
    size_t zero_len = off;
    // ---- non-zeroed ----
    int*   deg    = (int*)  alloc((size_t)N * 4);
    float* acc1   = (float*)alloc((size_t)N * 16);
    float* acc2   = (float*)alloc((size_t)N * 16);
    float* gB     = (float*)alloc((size_t)N * 16);
    float* z      = (float*)alloc((size_t)N * 4);
    int*   le     = (int*)  alloc((size_t)CAP_I * 4);
    int*   lt     = (int*)  alloc((size_t)CAP_I * 4);
    int*   s1list = (int*)  alloc((size_t)CAP_S1 * 4);
    int*   l2s    = (int*)  alloc((size_t)CAP_L2 * 4);
    int*   l2t    = (int*)  alloc((size_t)CAP_L2 * 4);
    int*   l1s    = (int*)  alloc((size_t)CAP_L1 * 4);
    int*   l1t    = (int*)  alloc((size_t)CAP_L1 * 4);

    float* out_score = (float*)d_out;
    float* out_tgt   = out_score + E;

    int edgeBlocksA = (nvec + 255) / 256;
    if (edgeBlocksA > 2048) edgeBlocksA = 2048;

    (void)hipMemsetAsync(zero_base, 0, zero_len, stream);

    k_passA<<<edgeBlocksA, 256, 0, stream>>>((const int4*)src, (const int4*)dst, nvec, nodep,
                                             cnts, le, lt, bmT, bmS1, bmS0, cbmT, cbmS1,
                                             s1list, deg, (float4*)acc1, (float4*)acc2);
    k_passB<<<2048, 256, 0, stream>>>(src, (const int4*)dst, nvec, cbmT, bmT,
                                      bmS1, bmS0, cbmS1, cnts, l2s, l2t, s1list,
                                      deg, (float4*)acc1, (float4*)acc2);
    k_passC<<<2048, 256, 0, stream>>>(src, (const int4*)dst, nvec, cbmS1, bmS1, bmS0,
                                      cnts, l1s, l1t, deg);
    k_passD<<<4096, 256, 0, stream>>>((const int4*)dst, nvec, bmS0, deg,
                                      (vfloat4*)out_score, (vfloat4*)out_tgt);
    k_conv1<<<256, 256, 0, stream>>>(cnts, l1s, l1t, x, W1, deg, acc1);
    k_tail<<<1, 1024, 0, stream>>>(cnts, s1list, l2s, l2t, le, lt, x, W1, b1, W2, b2,
                                   Wr, br, deg, acc1, acc2, gB, z, out_score, out_tgt);
}